// Round 11
// baseline (14.773 us; speedup 1.0000x reference)
//
#include <hip/hip_runtime.h>
#include <math.h>

#define NROWS 100000
#define EENS 10
#define NTILES 3125          // NROWS/32, exact
#define GWAVES 2048          // 512 blocks x 4 waves

// NORM_CONST = 1/((2*pi)^2 * sigma^4), sigma=0.1
#define NORM_CONST_F 253.30295910584444f
// EXP2_SCALE = -0.5/sigma^2 * log2(e)
#define EXP2_SCALE (-72.13475204444817f)
#define M2_CONST   (144.26950408889634f)   // -2*EXP2_SCALE
#define ARG_THRESH (-18.0f)

typedef _Float16 h8 __attribute__((ext_vector_type(8)));
typedef float    f4 __attribute__((ext_vector_type(4)));

// R11: R10's MFMA kernel + grid-stride tiles. 2048 waves, each stages
// B-frags/mean/weights ONCE, then processes tiles gw and gw+2048.
// Fixes 391-block CU imbalance (2-vs-1 blocks/CU -> ~12.2 tiles/CU even).

__global__ __launch_bounds__(256) void fused_kernel(
    const float* __restrict__ x,                   // N x 4
    const float* __restrict__ ensemble_probs,      // N x 10
    const float* __restrict__ ensemble_norm_probs, // N x 1
    const float* __restrict__ weights,             // 10
    const float* __restrict__ centers,             // 256 x 4
    const float* __restrict__ coefficients,        // 256
    float* __restrict__ out)                       // [0,N) ensemble, [N,2N) net_out
{
    const int t    = threadIdx.x;
    const int lane = t & 63;
    const int wid  = t >> 6;                 // 0..3
    const int gw   = blockIdx.x * 4 + wid;   // global wave 0..2047
    const int lr   = lane & 15;
    const int g    = lane >> 4;

    // ---- once per wave: mean(coefficients) ----
    const float4 cq = ((const float4*)coefficients)[lane];
    float ms = (cq.x + cq.y) + (cq.z + cq.w);
    #pragma unroll
    for (int off = 32; off > 0; off >>= 1) ms += __shfl_down(ms, off, 64);
    const float mean = __builtin_amdgcn_readfirstlane(ms) * (1.0f / 256.0f);

    // ---- once per wave: stage 16 B-fragments (two-level f16 split) ----
    h8 bf[16]; float As[16], wcv[16];
    #pragma unroll
    for (int T = 0; T < 16; ++T) {
        const float4 cv = ((const float4*)centers)[T * 16 + lr];
        const _Float16 h0 = (_Float16)cv.x, h1 = (_Float16)cv.y,
                       h2 = (_Float16)cv.z, h3 = (_Float16)cv.w;
        h8 b;
        b[0] = h0; b[1] = h1; b[2] = h2; b[3] = h3;
        b[4] = (_Float16)(cv.x - (float)h0);
        b[5] = (_Float16)(cv.y - (float)h1);
        b[6] = (_Float16)(cv.z - (float)h2);
        b[7] = (_Float16)(cv.w - (float)h3);
        bf[T] = b;
        float n2 = cv.x * cv.x;
        n2 = fmaf(cv.y, cv.y, n2);
        n2 = fmaf(cv.z, cv.z, n2);
        n2 = fmaf(cv.w, cv.w, n2);
        As[T]  = EXP2_SCALE * n2;
        wcv[T] = coefficients[T * 16 + lr] - mean;
    }

    // ---- once per wave: ensemble weights ----
    float wv[EENS];
    float wsum = 0.0f;
    #pragma unroll
    for (int e = 0; e < EENS; ++e) { wv[e] = weights[e]; wsum += wv[e]; }
    const float wnorm = 1.0f - wsum;

    // ---- grid-stride over 32-row tiles ----
    for (int tile = gw; tile < NTILES; tile += GWAVES) {
        const int wbase = tile * 32;

        const float4 xa = ((const float4*)x)[wbase + lr];
        const float4 xb = ((const float4*)x)[wbase + 16 + lr];

        float hsa = xa.x * xa.x;
        hsa = fmaf(xa.y, xa.y, hsa); hsa = fmaf(xa.z, xa.z, hsa); hsa = fmaf(xa.w, xa.w, hsa);
        hsa *= EXP2_SCALE;
        float hsb = xb.x * xb.x;
        hsb = fmaf(xb.y, xb.y, hsb); hsb = fmaf(xb.z, xb.z, hsb); hsb = fmaf(xb.w, xb.w, hsb);
        hsb *= EXP2_SCALE;

        const float HA0 = __shfl(hsa, g * 4 + 0, 64), HA1 = __shfl(hsa, g * 4 + 1, 64),
                    HA2 = __shfl(hsa, g * 4 + 2, 64), HA3 = __shfl(hsa, g * 4 + 3, 64);
        const float HB0 = __shfl(hsb, g * 4 + 0, 64), HB1 = __shfl(hsb, g * 4 + 1, 64),
                    HB2 = __shfl(hsb, g * 4 + 2, 64), HB3 = __shfl(hsb, g * 4 + 3, 64);

        const float a0f = (float)(_Float16)xa.x, a1f = (float)(_Float16)xa.y,
                    a2f = (float)(_Float16)xa.z, a3f = (float)(_Float16)xa.w;
        const float b0f = (float)(_Float16)xb.x, b1f = (float)(_Float16)xb.y,
                    b2f = (float)(_Float16)xb.z, b3f = (float)(_Float16)xb.w;

        const float sa0 = (g == 0) ? a0f : (g == 1) ? (xa.x - a0f) : 0.f;
        const float sa1 = (g == 0) ? a1f : (g == 1) ? (xa.y - a1f) : 0.f;
        const float sa2 = (g == 0) ? a2f : (g == 1) ? (xa.z - a2f) : 0.f;
        const float sa3 = (g == 0) ? a3f : (g == 1) ? (xa.w - a3f) : 0.f;
        const float sb0 = (g == 0) ? b0f : (g == 1) ? (xb.x - b0f) : 0.f;
        const float sb1 = (g == 0) ? b1f : (g == 1) ? (xb.y - b1f) : 0.f;
        const float sb2 = (g == 0) ? b2f : (g == 1) ? (xb.z - b2f) : 0.f;
        const float sb3 = (g == 0) ? b3f : (g == 1) ? (xb.w - b3f) : 0.f;

        h8 afA, afB;
        afA[0] = (_Float16)sa0; afA[1] = (_Float16)sa1; afA[2] = (_Float16)sa2; afA[3] = (_Float16)sa3;
        afA[4] = afA[0]; afA[5] = afA[1]; afA[6] = afA[2]; afA[7] = afA[3];
        afB[0] = (_Float16)sb0; afB[1] = (_Float16)sb1; afB[2] = (_Float16)sb2; afB[3] = (_Float16)sb3;
        afB[4] = afB[0]; afB[5] = afB[1]; afB[6] = afB[2]; afB[7] = afB[3];

        f4 accA = {0.f, 0.f, 0.f, 0.f};
        f4 accB = {0.f, 0.f, 0.f, 0.f};
        const f4 z4 = {0.f, 0.f, 0.f, 0.f};

        #pragma unroll
        for (int T = 0; T < 16; ++T) {
            const f4 dA = __builtin_amdgcn_mfma_f32_16x16x32_f16(afA, bf[T], z4, 0, 0, 0);
            const f4 dB = __builtin_amdgcn_mfma_f32_16x16x32_f16(afB, bf[T], z4, 0, 0, 0);

            const float baseA = As[T];
            const float ra0 = fmaf(M2_CONST, dA[0], HA0 + baseA);
            const float ra1 = fmaf(M2_CONST, dA[1], HA1 + baseA);
            const float ra2 = fmaf(M2_CONST, dA[2], HA2 + baseA);
            const float ra3 = fmaf(M2_CONST, dA[3], HA3 + baseA);
            const float mxa = fmaxf(fmaxf(ra0, ra1), fmaxf(ra2, ra3));
            if (__any(mxa > ARG_THRESH)) {
                accA[0] = fmaf(__builtin_amdgcn_exp2f(ra0), wcv[T], accA[0]);
                accA[1] = fmaf(__builtin_amdgcn_exp2f(ra1), wcv[T], accA[1]);
                accA[2] = fmaf(__builtin_amdgcn_exp2f(ra2), wcv[T], accA[2]);
                accA[3] = fmaf(__builtin_amdgcn_exp2f(ra3), wcv[T], accA[3]);
            }

            const float rb0 = fmaf(M2_CONST, dB[0], HB0 + baseA);
            const float rb1 = fmaf(M2_CONST, dB[1], HB1 + baseA);
            const float rb2 = fmaf(M2_CONST, dB[2], HB2 + baseA);
            const float rb3 = fmaf(M2_CONST, dB[3], HB3 + baseA);
            const float mxb = fmaxf(fmaxf(rb0, rb1), fmaxf(rb2, rb3));
            if (__any(mxb > ARG_THRESH)) {
                accB[0] = fmaf(__builtin_amdgcn_exp2f(rb0), wcv[T], accB[0]);
                accB[1] = fmaf(__builtin_amdgcn_exp2f(rb1), wcv[T], accB[1]);
                accB[2] = fmaf(__builtin_amdgcn_exp2f(rb2), wcv[T], accB[2]);
                accB[3] = fmaf(__builtin_amdgcn_exp2f(rb3), wcv[T], accB[3]);
            }
        }

        // reduce over the 16 cols (lanes within same group)
        #pragma unroll
        for (int msk = 1; msk <= 8; msk <<= 1) {
            accA[0] += __shfl_xor(accA[0], msk, 64);
            accA[1] += __shfl_xor(accA[1], msk, 64);
            accA[2] += __shfl_xor(accA[2], msk, 64);
            accA[3] += __shfl_xor(accA[3], msk, 64);
            accB[0] += __shfl_xor(accB[0], msk, 64);
            accB[1] += __shfl_xor(accB[1], msk, 64);
            accB[2] += __shfl_xor(accB[2], msk, 64);
            accB[3] += __shfl_xor(accB[3], msk, 64);
        }
        if (lr == 0) {
            const int rbA = wbase + g * 4;
            out[NROWS + rbA + 0] = accA[0] * NORM_CONST_F;
            out[NROWS + rbA + 1] = accA[1] * NORM_CONST_F;
            out[NROWS + rbA + 2] = accA[2] * NORM_CONST_F;
            out[NROWS + rbA + 3] = accA[3] * NORM_CONST_F;
            const int rbB = rbA + 16;
            out[NROWS + rbB + 0] = accB[0] * NORM_CONST_F;
            out[NROWS + rbB + 1] = accB[1] * NORM_CONST_F;
            out[NROWS + rbB + 2] = accB[2] * NORM_CONST_F;
            out[NROWS + rbB + 3] = accB[3] * NORM_CONST_F;
        }

        // ensemble for this tile's 32 rows
        if (lane < 32) {
            const int r = wbase + lane;
            float ens = ensemble_norm_probs[r] * wnorm;
            const float2* pr = (const float2*)(ensemble_probs + (size_t)r * EENS);
            #pragma unroll
            for (int e2 = 0; e2 < EENS / 2; ++e2) {
                const float2 p = pr[e2];
                ens = fmaf(p.x, wv[2 * e2 + 0], ens);
                ens = fmaf(p.y, wv[2 * e2 + 1], ens);
            }
            out[r] = ens;
        }
    }
}

extern "C" void kernel_launch(void* const* d_in, const int* in_sizes, int n_in,
                              void* d_out, int out_size, void* d_ws, size_t ws_size,
                              hipStream_t stream) {
    const float* x       = (const float*)d_in[0];
    const float* eprobs  = (const float*)d_in[1];
    const float* enorm   = (const float*)d_in[2];
    const float* weights = (const float*)d_in[3];
    const float* centers = (const float*)d_in[4];
    const float* coeffs  = (const float*)d_in[5];
    float* out = (float*)d_out;

    fused_kernel<<<512, 256, 0, stream>>>(
        x, eprobs, enorm, weights, centers, coeffs, out);
}

// Round 12
// 13.668 us; speedup vs baseline: 1.0808x; 1.0808x over previous
//
#include <hip/hip_runtime.h>
#include <math.h>

#define NROWS 100000
#define MCENT 256
#define EENS 10
#define WAVES 8

// NORM_CONST = 1/((2*pi)^2 * sigma^4), sigma=0.1
#define NORM_CONST_F 253.30295910584444f
// -0.5/sigma^2 * log2(e) = -50 * 1.4426950408889634
#define EXP2_SCALE (-72.13475204444817f)

// R12 = R9 (best measured: 13.68 us). 2 rows/thread + wave-uniform skip.
// Dropped terms (d2 >= 0.25) each contribute <= 253*3.7*e^{-12.5} ~ 3.5e-3.
#define DROP_T 0.25f

__global__ __launch_bounds__(512) void fused_kernel(
    const float* __restrict__ x,                   // N x 4
    const float* __restrict__ ensemble_probs,      // N x 10
    const float* __restrict__ ensemble_norm_probs, // N x 1
    const float* __restrict__ weights,             // 10
    const float* __restrict__ centers,             // 256 x 4
    const float* __restrict__ coefficients,        // 256
    float* __restrict__ out)                       // [0,N) ensemble, [N,2N) net_out
{
    __shared__ float s_p1[WAVES][2][64];
    __shared__ float s_p2[WAVES][2][64];

    const int t = threadIdx.x;
    const int lane = t & 63;
    const int wid = __builtin_amdgcn_readfirstlane(t >> 6);

    const int base = blockIdx.x * 128;
    const int r0 = base + lane;
    const int r1 = r0 + 64;
    const int rc0 = (r0 < NROWS) ? r0 : (NROWS - 1);
    const int rc1 = (r1 < NROWS) ? r1 : (NROWS - 1);

    const float4 xa = ((const float4*)x)[rc0];
    const float4 xb = ((const float4*)x)[rc1];

    // each wave owns a 32-center chunk; wave-uniform addr -> s_load
    const float4* __restrict__ C = (const float4*)centers + wid * 32;
    const float*  __restrict__ K = coefficients + wid * 32;

    float a1 = 0.f, a2 = 0.f;   // row r0: sum cf*e, sum e
    float b1 = 0.f, b2 = 0.f;   // row r1

    #pragma unroll 8
    for (int k = 0; k < 32; ++k) {
        const float4 c = C[k];

        const float dxa = xa.x - c.x, dya = xa.y - c.y,
                    dza = xa.z - c.z, dwa = xa.w - c.w;
        float d2a = dxa * dxa;
        d2a = fmaf(dya, dya, d2a);
        d2a = fmaf(dza, dza, d2a);
        d2a = fmaf(dwa, dwa, d2a);

        const float dxb = xb.x - c.x, dyb = xb.y - c.y,
                    dzb = xb.z - c.z, dwb = xb.w - c.w;
        float d2b = dxb * dxb;
        d2b = fmaf(dyb, dyb, d2b);
        d2b = fmaf(dzb, dzb, d2b);
        d2b = fmaf(dwb, dwb, d2b);

        // one wave-uniform test for both rows (~21% of wave-iters live)
        if (__builtin_expect(__any(fminf(d2a, d2b) < DROP_T), 0)) {
            const float cf = K[k];
            const float ea = __builtin_amdgcn_exp2f(d2a * EXP2_SCALE);
            const float eb = __builtin_amdgcn_exp2f(d2b * EXP2_SCALE);
            a1 = fmaf(cf, ea, a1);
            a2 += ea;
            b1 = fmaf(cf, eb, b1);
            b2 += eb;
        }
    }

    s_p1[wid][0][lane] = a1;  s_p2[wid][0][lane] = a2;
    s_p1[wid][1][lane] = b1;  s_p2[wid][1][lane] = b2;
    __syncthreads();

    if (wid < 2) {
        // mean of coefficients (redundant per wave): 64 lanes x float4
        const float4 cf4 = ((const float4*)coefficients)[lane];
        float s = (cf4.x + cf4.y) + (cf4.z + cf4.w);
        #pragma unroll
        for (int off = 32; off > 0; off >>= 1) s += __shfl_down(s, off, 64);
        const float mean = __builtin_amdgcn_readfirstlane(s) * (1.0f / 256.0f);

        const int rr = base + wid * 64 + lane;
        if (rr < NROWS) {
            float P1 = 0.f, P2 = 0.f;
            #pragma unroll
            for (int w = 0; w < WAVES; ++w) {
                P1 += s_p1[w][wid][lane];
                P2 += s_p2[w][wid][lane];
            }
            out[NROWS + rr] = (P1 - mean * P2) * NORM_CONST_F;
        }
    } else if (wid < 4) {
        const int half = wid - 2;
        const int rr = base + half * 64 + lane;
        if (rr < NROWS) {
            float wv[EENS];
            float wsum = 0.0f;
            #pragma unroll
            for (int e = 0; e < EENS; ++e) { wv[e] = weights[e]; wsum += wv[e]; }
            float ens = ensemble_norm_probs[rr] * (1.0f - wsum);
            const float2* pr = (const float2*)(ensemble_probs + (size_t)rr * EENS);
            #pragma unroll
            for (int e2 = 0; e2 < EENS / 2; ++e2) {
                const float2 p = pr[e2];
                ens = fmaf(p.x, wv[2 * e2 + 0], ens);
                ens = fmaf(p.y, wv[2 * e2 + 1], ens);
            }
            out[rr] = ens;
        }
    }
}

extern "C" void kernel_launch(void* const* d_in, const int* in_sizes, int n_in,
                              void* d_out, int out_size, void* d_ws, size_t ws_size,
                              hipStream_t stream) {
    const float* x       = (const float*)d_in[0];
    const float* eprobs  = (const float*)d_in[1];
    const float* enorm   = (const float*)d_in[2];
    const float* weights = (const float*)d_in[3];
    const float* centers = (const float*)d_in[4];
    const float* coeffs  = (const float*)d_in[5];
    float* out = (float*)d_out;

    const int blocks = (NROWS + 127) / 128;  // 782 blocks x 8 waves
    fused_kernel<<<blocks, 512, 0, stream>>>(
        x, eprobs, enorm, weights, centers, coeffs, out);
}